// Round 4
// baseline (225.006 us; speedup 1.0000x reference)
//
#include <hip/hip_runtime.h>
#include <math.h>

#define BB 16
#define NN 4096
#define DD 128
#define KK 256          // C*P = 4*64
#define NROWS (BB*NN)   // 65536
#define WIN 7
#define HWIN 3
#define ALPHA 0.5f
#define EPS 1e-5f

typedef __attribute__((ext_vector_type(8))) short bf16x8;
typedef __attribute__((ext_vector_type(4))) float f32x4;

__device__ __forceinline__ unsigned short f2b(float f) {     // f32 -> bf16 RNE
    unsigned u = __float_as_uint(f);
    u += 0x7FFFu + ((u >> 16) & 1u);
    return (unsigned short)(u >> 16);
}
__device__ __forceinline__ float b2f_lo(unsigned v) { return __uint_as_float(v << 16); }
__device__ __forceinline__ float b2f_hi(unsigned v) { return __uint_as_float(v & 0xFFFF0000u); }
__device__ __forceinline__ float lrelu(float v) { return v >= 0.f ? v : 0.1f * v; }

__device__ __forceinline__ uint4 pack8(float4 a, float4 b) {
    uint4 v;
    v.x = (unsigned)f2b(a.x)  | ((unsigned)f2b(a.y)  << 16);
    v.y = (unsigned)f2b(a.z)  | ((unsigned)f2b(a.w)  << 16);
    v.z = (unsigned)f2b(b.x)  | ((unsigned)f2b(b.y)  << 16);
    v.w = (unsigned)f2b(b.z)  | ((unsigned)f2b(b.w)  << 16);
    return v;
}

// ---------------------------------------------------------------------------
// Kernel P: W f32 [128][256] -> bf16 FRAGMENT-MAJOR image.
// Wfrag[f*64 + lane], f = (wn*2+n)*8+k : lane's B-fragment = W[d][c..c+8)
// with d = 32*wn+16*n+(lane&15), c = k*32+(lane>>4)*8. 64 KB total.
// ---------------------------------------------------------------------------
__global__ __launch_bounds__(256) void k_prep(
    const float* __restrict__ W, uint4* __restrict__ Wfrag)
{
    const int id   = blockIdx.x * 256 + threadIdx.x;   // 0..4095
    const int lane = id & 63, f = id >> 6;
    const int k  = f & 7, n = (f >> 3) & 1, wn = f >> 4;
    const int d  = 32 * wn + 16 * n + (lane & 15);
    const int c  = k * 32 + (lane >> 4) * 8;
    const float4 a = *(const float4*)(&W[(size_t)d * KK + c]);
    const float4 b = *(const float4*)(&W[(size_t)d * KK + c + 4]);
    Wfrag[id] = pack8(a, b);
}

// ---------------------------------------------------------------------------
// Kernel A: h = bf16mfma(X @ W^T) + b (h bf16) + per-feature sum/sumsq.
// 512 blocks x 512 threads, 256 rows/block, 4 subtiles of 64 rows,
// X double-buffered 2x32 KB (XOR-swizzled), W fragments in registers.
// ---------------------------------------------------------------------------
__device__ __forceinline__ void stage_load(const float* __restrict__ X, int grow0,
                                           int t, float4* ra, float4* rb)
{
    #pragma unroll
    for (int p = 0; p < 4; ++p) {
        const int j = t + p * 512;           // 0..2047 chunks of 8 floats
        const int r = j >> 5, c8 = j & 31;
        const float* gp = X + (size_t)(grow0 + r) * KK + c8 * 8;
        ra[p] = *(const float4*)(gp);
        rb[p] = *(const float4*)(gp + 4);
    }
}
__device__ __forceinline__ void stage_write(unsigned short* dst, int t,
                                            const float4* ra, const float4* rb)
{
    #pragma unroll
    for (int p = 0; p < 4; ++p) {
        const int j = t + p * 512;
        const int r = j >> 5, c8 = j & 31;
        const int off = r * 512 + ((c8 * 16) ^ ((r & 7) << 4));
        *(uint4*)((char*)dst + off) = pack8(ra[p], rb[p]);
    }
}

__global__ __launch_bounds__(512, 4) void k_embed(
    const float* __restrict__ x,
    const float* __restrict__ xt,
    const uint4* __restrict__ Wfrag,
    const float* __restrict__ bvec,
    unsigned short* __restrict__ h_out,   // [2][NROWS][DD] bf16
    float* __restrict__ sums)             // [2][2][DD]
{
    __shared__ unsigned short Xs[2][64 * 256];   // 2 x 32 KB

    const int blk  = blockIdx.x;          // 512
    const int src  = blk >> 8;
    const int tile = blk & 255;
    const int row0 = tile * 256;
    const float* __restrict__ X = src ? xt : x;
    unsigned short* __restrict__ H = h_out + (size_t)src * NROWS * DD;

    const int t    = threadIdx.x;
    const int lane = t & 63;
    const int w    = t >> 6;              // 0..7
    const int wm   = w & 1;               // row half (32 rows)
    const int wn   = w >> 1;              // col quarter (32 cols)
    const int l15  = lane & 15;
    const int lg   = lane >> 4;

    // W fragments -> registers (coalesced, L2-resident)
    bf16x8 breg[2][8];
    #pragma unroll
    for (int n = 0; n < 2; ++n)
        #pragma unroll
        for (int k = 0; k < 8; ++k) {
            uint4 u = Wfrag[((wn * 2 + n) * 8 + k) * 64 + lane];
            breg[n][k] = *(bf16x8*)&u;
        }

    float4 ra[4], rb[4];
    stage_load(X, row0, t, ra, rb);
    stage_write(&Xs[0][0], t, ra, rb);
    __syncthreads();

    const float bv0 = bvec[32 * wn + l15];
    const float bv1 = bvec[32 * wn + 16 + l15];
    float s0 = 0.f, s1 = 0.f, q0 = 0.f, q1 = 0.f;

    for (int st = 0; st < 4; ++st) {
        const int cur = st & 1;
        f32x4 acc[2][2];
        #pragma unroll
        for (int m = 0; m < 2; ++m)
            #pragma unroll
            for (int n = 0; n < 2; ++n)
                #pragma unroll
                for (int j = 0; j < 4; ++j) acc[m][n][j] = 0.f;

        const char* xb = (const char*)&Xs[cur][0];
        #pragma unroll
        for (int k = 0; k < 8; ++k) {
            bf16x8 af[2];
            #pragma unroll
            for (int m = 0; m < 2; ++m) {
                const int r = 32 * wm + 16 * m + l15;
                const int addr = r * 512 + (((k * 64) + lg * 16) ^ ((r & 7) << 4));
                af[m] = *(const bf16x8*)(xb + addr);
            }
            acc[0][0] = __builtin_amdgcn_mfma_f32_16x16x32_bf16(af[0], breg[0][k], acc[0][0], 0, 0, 0);
            acc[0][1] = __builtin_amdgcn_mfma_f32_16x16x32_bf16(af[0], breg[1][k], acc[0][1], 0, 0, 0);
            acc[1][0] = __builtin_amdgcn_mfma_f32_16x16x32_bf16(af[1], breg[0][k], acc[1][0], 0, 0, 0);
            acc[1][1] = __builtin_amdgcn_mfma_f32_16x16x32_bf16(af[1], breg[1][k], acc[1][1], 0, 0, 0);
        }

        // issue next-subtile global loads; epilogue below hides their latency
        if (st < 3) stage_load(X, row0 + (st + 1) * 64, t, ra, rb);

        // epilogue: bias, bf16 store, sums.  C/D: col=lane&15, row=lg*4+j
        #pragma unroll
        for (int m = 0; m < 2; ++m) {
            #pragma unroll
            for (int j = 0; j < 4; ++j) {
                const int row = row0 + st * 64 + 32 * wm + 16 * m + lg * 4 + j;
                const float v0 = acc[m][0][j] + bv0;
                const float v1 = acc[m][1][j] + bv1;
                H[(size_t)row * DD + 32 * wn + l15]      = f2b(v0);
                H[(size_t)row * DD + 32 * wn + 16 + l15] = f2b(v1);
                s0 += v0; q0 += v0 * v0;
                s1 += v1; q1 += v1 * v1;
            }
        }

        // write next tile (other waves may still be in MFMA of cur -- safe:
        // Xs[cur^1] was last read before barrier st-1)
        if (st < 3) stage_write(&Xs[cur ^ 1][0], t, ra, rb);
        __syncthreads();
    }

    // reduce sums: intra-wave over lane groups, cross-wave via LDS
    s0 += __shfl_xor(s0, 16); s0 += __shfl_xor(s0, 32);
    s1 += __shfl_xor(s1, 16); s1 += __shfl_xor(s1, 32);
    q0 += __shfl_xor(q0, 16); q0 += __shfl_xor(q0, 32);
    q1 += __shfl_xor(q1, 16); q1 += __shfl_xor(q1, 32);
    float* red = (float*)&Xs[0][0];
    if (lane < 16) {
        red[(w * 2 + 0) * 16 + l15]       = s0;
        red[(w * 2 + 1) * 16 + l15]       = s1;
        red[256 + (w * 2 + 0) * 16 + l15] = q0;
        red[256 + (w * 2 + 1) * 16 + l15] = q1;
    }
    __syncthreads();
    if (t < 128) {
        const int wn_ = t >> 5, n_ = (t >> 4) & 1, li = t & 15;
        float S = 0.f, Q = 0.f;
        #pragma unroll
        for (int wm_ = 0; wm_ < 2; ++wm_) {
            const int w_ = wn_ * 2 + wm_;
            S += red[(w_ * 2 + n_) * 16 + li];
            Q += red[256 + (w_ * 2 + n_) * 16 + li];
        }
        atomicAdd(&sums[src * 256 + t], S);
        atomicAdd(&sums[src * 256 + 128 + t], Q);
    }
}

// ---------------------------------------------------------------------------
// Kernel C: stats finalize (folded in) + normalize + leaky, windowed sim,
// masked softmax, weighted blend. xt window staged to LDS bf16.
// ---------------------------------------------------------------------------
__global__ __launch_bounds__(256) void k_attn(
    const float* __restrict__ x,
    const float* __restrict__ xt,
    const unsigned short* __restrict__ h,   // [2][NROWS][DD] bf16
    const float* __restrict__ sums,         // [2][2][DD]
    const float* __restrict__ gamma,
    const float* __restrict__ beta,
    float* __restrict__ out,
    float* __restrict__ feat)
{
    const int blk  = blockIdx.x;
    const int bb   = blk >> 7;
    const int tile = blk & 127;
    const int n0   = tile * 32;
    const int t    = threadIdx.x;

    __shared__ float ex[32][132];
    __shared__ float et[38][132];           // later overlaid with xt window (bf16)
    __shared__ float attnw[32][8];
    __shared__ float ssl[512];              // [2][2][DD] scale/shift

    const unsigned short* __restrict__ Hx = h;
    const unsigned short* __restrict__ Ht = h + (size_t)NROWS * DD;
    const size_t rowbase = (size_t)bb * NN;

    // phase 0: recompute scale/shift from global sums (cheap, saves a kernel)
    {
        const int s_ = t >> 7, d = t & 127;
        const float invn = 1.0f / (float)NROWS;
        const float mean = sums[s_ * 256 + d] * invn;
        const float var  = sums[s_ * 256 + 128 + d] * invn - mean * mean;
        const float sc   = gamma[d] / sqrtf(var + EPS);
        ssl[s_ * 256 + d]       = sc;
        ssl[s_ * 256 + 128 + d] = beta[d] - mean * sc;
    }
    __syncthreads();

    // phase 1: emb_x / emb_t -> LDS f32 (normalize + leaky on the fly)
    #pragma unroll
    for (int p = 0; p < 2; ++p) {
        const int j = t + p * 256;
        const int r = j >> 4, c8 = j & 15;
        const uint4 u = *(const uint4*)(&Hx[(rowbase + n0 + r) * DD + c8 * 8]);
        const float4 sca = *(const float4*)(&ssl[c8 * 8]);
        const float4 scb = *(const float4*)(&ssl[c8 * 8 + 4]);
        const float4 sha = *(const float4*)(&ssl[128 + c8 * 8]);
        const float4 shb = *(const float4*)(&ssl[128 + c8 * 8 + 4]);
        float* dst = &ex[r][c8 * 8];
        dst[0] = lrelu(b2f_lo(u.x) * sca.x + sha.x);
        dst[1] = lrelu(b2f_hi(u.x) * sca.y + sha.y);
        dst[2] = lrelu(b2f_lo(u.y) * sca.z + sha.z);
        dst[3] = lrelu(b2f_hi(u.y) * sca.w + sha.w);
        dst[4] = lrelu(b2f_lo(u.z) * scb.x + shb.x);
        dst[5] = lrelu(b2f_hi(u.z) * scb.y + shb.y);
        dst[6] = lrelu(b2f_lo(u.w) * scb.z + shb.z);
        dst[7] = lrelu(b2f_hi(u.w) * scb.w + shb.w);
    }
    #pragma unroll
    for (int p = 0; p < 3; ++p) {
        const int j = t + p * 256;
        if (j < 608) {
            const int r = j >> 4, c8 = j & 15;
            int g = n0 - HWIN + r;
            g = min(max(g, 0), NN - 1);
            const uint4 u = *(const uint4*)(&Ht[(rowbase + g) * DD + c8 * 8]);
            const float4 sca = *(const float4*)(&ssl[256 + c8 * 8]);
            const float4 scb = *(const float4*)(&ssl[256 + c8 * 8 + 4]);
            const float4 sha = *(const float4*)(&ssl[384 + c8 * 8]);
            const float4 shb = *(const float4*)(&ssl[384 + c8 * 8 + 4]);
            float* dst = &et[r][c8 * 8];
            dst[0] = lrelu(b2f_lo(u.x) * sca.x + sha.x);
            dst[1] = lrelu(b2f_hi(u.x) * sca.y + sha.y);
            dst[2] = lrelu(b2f_lo(u.y) * sca.z + sha.z);
            dst[3] = lrelu(b2f_hi(u.y) * sca.w + sha.w);
            dst[4] = lrelu(b2f_lo(u.z) * scb.x + shb.x);
            dst[5] = lrelu(b2f_hi(u.z) * scb.y + shb.y);
            dst[6] = lrelu(b2f_lo(u.w) * scb.z + shb.z);
            dst[7] = lrelu(b2f_hi(u.w) * scb.w + shb.w);
        }
    }
    __syncthreads();

    // phase 2: sim (224 threads: 32 n x 7 w dots of length 128)
    if (t < 224) {
        const int n_i = t / 7;
        const int wv  = t % 7;
        const float* a = &ex[n_i][0];
        const float* b = &et[n_i + wv][0];
        float acc = 0.f;
        #pragma unroll
        for (int d4 = 0; d4 < 128; d4 += 4) {
            const float4 av = *(const float4*)(a + d4);
            const float4 bv = *(const float4*)(b + d4);
            acc += av.x * bv.x + av.y * bv.y + av.z * bv.z + av.w * bv.w;
        }
        feat[(rowbase + n0 + n_i) * WIN + wv] = acc;
        attnw[n_i][wv] = acc;
    }
    __syncthreads();

    // phase 3: xt window -> LDS bf16 (threads <224) || softmax (threads >=224)
    unsigned short* xts = (unsigned short*)&et[0][0];   // [38][256] bf16
    if (t < 224) {
        #pragma unroll
        for (int p = 0; p < 6; ++p) {
            const int j = t + p * 224;
            if (j < 1216) {
                const int r = j >> 5, c8 = j & 31;
                int g = n0 - HWIN + r;
                g = min(max(g, 0), NN - 1);
                const float* gp = &xt[(rowbase + g) * KK + c8 * 8];
                const float4 a = *(const float4*)(gp);
                const float4 b = *(const float4*)(gp + 4);
                *(uint4*)((char*)xts + r * 512 + c8 * 16) = pack8(a, b);
            }
        }
    } else {
        const int n_i = t - 224;
        const int n = n0 + n_i;
        float mx = -1e30f;
        #pragma unroll
        for (int wv = 0; wv < WIN; ++wv) {
            const int c = n + wv - HWIN;
            if (c >= 0 && c < NN) mx = fmaxf(mx, attnw[n_i][wv]);
        }
        float e[WIN];
        float esum = 0.f;
        #pragma unroll
        for (int wv = 0; wv < WIN; ++wv) {
            const int c = n + wv - HWIN;
            const bool valid = (c >= 0 && c < NN);
            e[wv] = valid ? expf(attnw[n_i][wv] - mx) : 0.f;
            esum += e[wv];
        }
        const float inv = 1.0f / esum;
        #pragma unroll
        for (int wv = 0; wv < WIN; ++wv) attnw[n_i][wv] = e[wv] * inv;
    }
    __syncthreads();

    // phase 4: out = alpha*x + (1-alpha) * sum_w attn[w] * xt_window (LDS)
    #pragma unroll
    for (int p = 0; p < 8; ++p) {
        const int idx = t + p * 256;
        const int n_i = idx >> 6, e4 = idx & 63;
        const int n = n0 + n_i;
        const float4 xv = *(const float4*)(&x[(rowbase + n) * KK + e4 * 4]);
        float4 acc = make_float4(0.f, 0.f, 0.f, 0.f);
        #pragma unroll
        for (int wv = 0; wv < WIN; ++wv) {
            const float aw = attnw[n_i][wv];
            const uint2 u = *(const uint2*)((const char*)xts + (n_i + wv) * 512 + e4 * 8);
            acc.x += aw * b2f_lo(u.x);
            acc.y += aw * b2f_hi(u.x);
            acc.z += aw * b2f_lo(u.y);
            acc.w += aw * b2f_hi(u.y);
        }
        float4 o;
        o.x = ALPHA * xv.x + (1.f - ALPHA) * acc.x;
        o.y = ALPHA * xv.y + (1.f - ALPHA) * acc.y;
        o.z = ALPHA * xv.z + (1.f - ALPHA) * acc.z;
        o.w = ALPHA * xv.w + (1.f - ALPHA) * acc.w;
        *(float4*)(&out[(rowbase + n) * KK + e4 * 4]) = o;
    }
}

// ---------------------------------------------------------------------------
extern "C" void kernel_launch(void* const* d_in, const int* in_sizes, int n_in,
                              void* d_out, int out_size, void* d_ws, size_t ws_size,
                              hipStream_t stream) {
    const float* x     = (const float*)d_in[0];
    const float* xt    = (const float*)d_in[1];
    const float* W     = (const float*)d_in[2];
    const float* bvec  = (const float*)d_in[3];
    const float* gamma = (const float*)d_in[4];
    const float* beta  = (const float*)d_in[5];

    float* out  = (float*)d_out;
    float* feat = out + (size_t)BB * NN * KK;

    char* ws = (char*)d_ws;
    unsigned short* h  = (unsigned short*)ws;                  // 32 MiB
    float* sums        = (float*)(ws + 33554432);              // 2 KiB
    unsigned char* Wfr = (unsigned char*)(ws + 33556480);      // 64 KiB

    hipMemsetAsync(sums, 0, 512 * sizeof(float), stream);
    k_prep<<<16, 256, 0, stream>>>(W, (uint4*)Wfr);
    k_embed<<<512, 512, 0, stream>>>(x, xt, (const uint4*)Wfr, bvec, h, sums);
    k_attn<<<2048, 256, 0, stream>>>(x, xt, h, sums, gamma, beta, out, feat);
}

// Round 5
// 218.913 us; speedup vs baseline: 1.0278x; 1.0278x over previous
//
#include <hip/hip_runtime.h>
#include <math.h>

#define BB 16
#define NN 4096
#define DD 128
#define KK 256          // C*P = 4*64
#define NROWS (BB*NN)   // 65536
#define WIN 7
#define HWIN 3
#define ALPHA 0.5f
#define EPS 1e-5f

typedef __attribute__((ext_vector_type(8))) short bf16x8;
typedef __attribute__((ext_vector_type(4))) float f32x4;

__device__ __forceinline__ unsigned short f2b(float f) {     // f32 -> bf16 RNE
    unsigned u = __float_as_uint(f);
    u += 0x7FFFu + ((u >> 16) & 1u);
    return (unsigned short)(u >> 16);
}
__device__ __forceinline__ float b2f_lo(unsigned v) { return __uint_as_float(v << 16); }
__device__ __forceinline__ float b2f_hi(unsigned v) { return __uint_as_float(v & 0xFFFF0000u); }
__device__ __forceinline__ float lrelu(float v) { return v >= 0.f ? v : 0.1f * v; }

__device__ __forceinline__ unsigned cvtpk(float lo, float hi) { // {bf16(hi),bf16(lo)}
    unsigned r;
    asm("v_cvt_pk_bf16_f32 %0, %1, %2" : "=v"(r) : "v"(lo), "v"(hi));
    return r;
}

__device__ __forceinline__ uint4 pack8(float4 a, float4 b) {
    uint4 v;
    v.x = (unsigned)f2b(a.x)  | ((unsigned)f2b(a.y)  << 16);
    v.y = (unsigned)f2b(a.z)  | ((unsigned)f2b(a.w)  << 16);
    v.z = (unsigned)f2b(b.x)  | ((unsigned)f2b(b.y)  << 16);
    v.w = (unsigned)f2b(b.z)  | ((unsigned)f2b(b.w)  << 16);
    return v;
}

#define GL2LDS(gp, lp) __builtin_amdgcn_global_load_lds( \
    (const __attribute__((address_space(1))) void*)(gp), \
    (__attribute__((address_space(3))) void*)(lp), 16, 0, 0)

// ---------------------------------------------------------------------------
// Kernel P: W f32 [128][256] -> bf16 FRAGMENT-MAJOR image.
// f = w*8 + k (wave w owns cols w*16..+16): Wfrag[f*64 + lane] =
// bf16x8 of W[d = w*16 + (lane&15)][c = k*32 + (lane>>4)*8 .. +8).
// ---------------------------------------------------------------------------
__global__ __launch_bounds__(256) void k_prep(
    const float* __restrict__ W, uint4* __restrict__ Wfrag)
{
    const int id   = blockIdx.x * 256 + threadIdx.x;   // 0..4095
    const int lane = id & 63, f = id >> 6;
    const int k = f & 7, w = f >> 3;
    const int d = w * 16 + (lane & 15);
    const int c = k * 32 + (lane >> 4) * 8;
    const float4 a = *(const float4*)(&W[(size_t)d * KK + c]);
    const float4 b = *(const float4*)(&W[(size_t)d * KK + c + 4]);
    Wfrag[id] = pack8(a, b);
}

// ---------------------------------------------------------------------------
// Kernel A: h = bf16mfma(X @ W^T) + b (h bf16) + per-feature sum/sumsq.
// 512 blocks x 512 threads, 256 rows/block, 8 subtiles of 32 rows.
// X staged f32 via global_load_lds (1 KB contiguous per instr), dbuf 2x32 KB.
// Swizzle: LDS 16B-unit p of row r holds global unit p ^ (r&15)
//   (achieved by permuting the per-lane GLOBAL source; LDS dest is linear).
// Read side XORs the same key -> conflict-free ds_read_b128.
// W fragments live in registers (32 VGPR/wave); f32->bf16 via v_cvt_pk.
// ---------------------------------------------------------------------------
__global__ __launch_bounds__(512, 4) void k_embed(
    const float* __restrict__ x,
    const float* __restrict__ xt,
    const uint4* __restrict__ Wfrag,
    const float* __restrict__ bvec,
    unsigned short* __restrict__ h_out,   // [2][NROWS][DD] bf16
    float* __restrict__ sums)             // [2][2][DD]
{
    __shared__ float Xs[2][32 * 256];     // 2 x 32 KB f32

    const int blk  = blockIdx.x;          // 512
    const int src  = blk >> 8;
    const int tile = blk & 255;
    const int row0 = tile * 256;
    const float* __restrict__ X = src ? xt : x;
    unsigned short* __restrict__ H = h_out + (size_t)src * NROWS * DD;

    const int t    = threadIdx.x;
    const int lane = t & 63;
    const int w    = t >> 6;              // 0..7 : cols w*16..+16
    const int l15  = lane & 15;
    const int lg   = lane >> 4;           // 0..3

    // W fragments -> registers (L2/L3-resident after first block)
    bf16x8 breg[8];
    #pragma unroll
    for (int k = 0; k < 8; ++k) {
        uint4 u = Wfrag[(w * 8 + k) * 64 + lane];
        breg[k] = *(bf16x8*)&u;
    }

    const float bv = bvec[w * 16 + l15];
    float s = 0.f, q = 0.f;

    // stage one 32-row subtile: wave w stages rows 4w..4w+3 (4 x 1KB instrs)
    #define STAGE(sub, b)                                                     \
    {                                                                         \
        const float* base_ = X + (size_t)(row0 + (sub) * 32) * KK;            \
        _Pragma("unroll")                                                     \
        for (int j_ = 0; j_ < 4; ++j_) {                                      \
            const int i_ = w * 4 + j_;                                        \
            const float* gp_ = base_ + i_ * KK + ((lane ^ (i_ & 15)) << 2);   \
            GL2LDS(gp_, &Xs[b][i_ * 256]);                                    \
        }                                                                     \
    }

    STAGE(0, 0);
    __syncthreads();

    #pragma unroll 1
    for (int st = 0; st < 8; ++st) {
        if (st < 7) STAGE(st + 1, (st + 1) & 1);

        const float* xb = &Xs[st & 1][0];
        f32x4 acc[2];
        #pragma unroll
        for (int m = 0; m < 2; ++m)
            #pragma unroll
            for (int j = 0; j < 4; ++j) acc[m][j] = 0.f;

        #pragma unroll
        for (int k = 0; k < 8; ++k) {
            const int u0 = k * 8 + lg * 2;            // 16B-unit of the k-slice
            #pragma unroll
            for (int m = 0; m < 2; ++m) {
                const float* pr = xb + (m * 16 + l15) * 256;
                const f32x4 a0 = *(const f32x4*)(pr + ((u0 ^ l15) << 2));
                const f32x4 a1 = *(const f32x4*)(pr + (((u0 + 1) ^ l15) << 2));
                uint4 uu;
                uu.x = cvtpk(a0[0], a0[1]);
                uu.y = cvtpk(a0[2], a0[3]);
                uu.z = cvtpk(a1[0], a1[1]);
                uu.w = cvtpk(a1[2], a1[3]);
                const bf16x8 av = *(const bf16x8*)&uu;
                acc[m] = __builtin_amdgcn_mfma_f32_16x16x32_bf16(av, breg[k], acc[m], 0, 0, 0);
            }
        }

        // epilogue: bias, bf16 store, sums.  C/D: col=lane&15, row=lg*4+j
        #pragma unroll
        for (int m = 0; m < 2; ++m) {
            #pragma unroll
            for (int j = 0; j < 4; ++j) {
                const int row = row0 + st * 32 + m * 16 + lg * 4 + j;
                const float v = acc[m][j] + bv;
                H[(size_t)row * DD + w * 16 + l15] = f2b(v);
                s += v; q += v * v;
            }
        }
        __syncthreads();
    }

    // per-col reduce: wave w exclusively owns cols w*16..+16 -> no LDS needed
    s += __shfl_xor(s, 16); s += __shfl_xor(s, 32);
    q += __shfl_xor(q, 16); q += __shfl_xor(q, 32);
    if (lane < 16) {
        atomicAdd(&sums[src * 256 + w * 16 + l15], s);
        atomicAdd(&sums[src * 256 + 128 + w * 16 + l15], q);
    }
    #undef STAGE
}

// ---------------------------------------------------------------------------
// Kernel C: stats finalize (folded in) + normalize + leaky, windowed sim,
// masked softmax, weighted blend. xt window staged to LDS bf16. (unchanged)
// ---------------------------------------------------------------------------
__global__ __launch_bounds__(256) void k_attn(
    const float* __restrict__ x,
    const float* __restrict__ xt,
    const unsigned short* __restrict__ h,   // [2][NROWS][DD] bf16
    const float* __restrict__ sums,         // [2][2][DD]
    const float* __restrict__ gamma,
    const float* __restrict__ beta,
    float* __restrict__ out,
    float* __restrict__ feat)
{
    const int blk  = blockIdx.x;
    const int bb   = blk >> 7;
    const int tile = blk & 127;
    const int n0   = tile * 32;
    const int t    = threadIdx.x;

    __shared__ float ex[32][132];
    __shared__ float et[38][132];           // later overlaid with xt window (bf16)
    __shared__ float attnw[32][8];
    __shared__ float ssl[512];              // [2][2][DD] scale/shift

    const unsigned short* __restrict__ Hx = h;
    const unsigned short* __restrict__ Ht = h + (size_t)NROWS * DD;
    const size_t rowbase = (size_t)bb * NN;

    // phase 0: recompute scale/shift from global sums
    {
        const int s_ = t >> 7, d = t & 127;
        const float invn = 1.0f / (float)NROWS;
        const float mean = sums[s_ * 256 + d] * invn;
        const float var  = sums[s_ * 256 + 128 + d] * invn - mean * mean;
        const float sc   = gamma[d] / sqrtf(var + EPS);
        ssl[s_ * 256 + d]       = sc;
        ssl[s_ * 256 + 128 + d] = beta[d] - mean * sc;
    }
    __syncthreads();

    // phase 1: emb_x / emb_t -> LDS f32 (normalize + leaky on the fly)
    #pragma unroll
    for (int p = 0; p < 2; ++p) {
        const int j = t + p * 256;
        const int r = j >> 4, c8 = j & 15;
        const uint4 u = *(const uint4*)(&Hx[(rowbase + n0 + r) * DD + c8 * 8]);
        const float4 sca = *(const float4*)(&ssl[c8 * 8]);
        const float4 scb = *(const float4*)(&ssl[c8 * 8 + 4]);
        const float4 sha = *(const float4*)(&ssl[128 + c8 * 8]);
        const float4 shb = *(const float4*)(&ssl[128 + c8 * 8 + 4]);
        float* dst = &ex[r][c8 * 8];
        dst[0] = lrelu(b2f_lo(u.x) * sca.x + sha.x);
        dst[1] = lrelu(b2f_hi(u.x) * sca.y + sha.y);
        dst[2] = lrelu(b2f_lo(u.y) * sca.z + sha.z);
        dst[3] = lrelu(b2f_hi(u.y) * sca.w + sha.w);
        dst[4] = lrelu(b2f_lo(u.z) * scb.x + shb.x);
        dst[5] = lrelu(b2f_hi(u.z) * scb.y + shb.y);
        dst[6] = lrelu(b2f_lo(u.w) * scb.z + shb.z);
        dst[7] = lrelu(b2f_hi(u.w) * scb.w + shb.w);
    }
    #pragma unroll
    for (int p = 0; p < 3; ++p) {
        const int j = t + p * 256;
        if (j < 608) {
            const int r = j >> 4, c8 = j & 15;
            int g = n0 - HWIN + r;
            g = min(max(g, 0), NN - 1);
            const uint4 u = *(const uint4*)(&Ht[(rowbase + g) * DD + c8 * 8]);
            const float4 sca = *(const float4*)(&ssl[256 + c8 * 8]);
            const float4 scb = *(const float4*)(&ssl[256 + c8 * 8 + 4]);
            const float4 sha = *(const float4*)(&ssl[384 + c8 * 8]);
            const float4 shb = *(const float4*)(&ssl[384 + c8 * 8 + 4]);
            float* dst = &et[r][c8 * 8];
            dst[0] = lrelu(b2f_lo(u.x) * sca.x + sha.x);
            dst[1] = lrelu(b2f_hi(u.x) * sca.y + sha.y);
            dst[2] = lrelu(b2f_lo(u.y) * sca.z + sha.z);
            dst[3] = lrelu(b2f_hi(u.y) * sca.w + sha.w);
            dst[4] = lrelu(b2f_lo(u.z) * scb.x + shb.x);
            dst[5] = lrelu(b2f_hi(u.z) * scb.y + shb.y);
            dst[6] = lrelu(b2f_lo(u.w) * scb.z + shb.z);
            dst[7] = lrelu(b2f_hi(u.w) * scb.w + shb.w);
        }
    }
    __syncthreads();

    // phase 2: sim (224 threads: 32 n x 7 w dots of length 128)
    if (t < 224) {
        const int n_i = t / 7;
        const int wv  = t % 7;
        const float* a = &ex[n_i][0];
        const float* b = &et[n_i + wv][0];
        float acc = 0.f;
        #pragma unroll
        for (int d4 = 0; d4 < 128; d4 += 4) {
            const float4 av = *(const float4*)(a + d4);
            const float4 bv = *(const float4*)(b + d4);
            acc += av.x * bv.x + av.y * bv.y + av.z * bv.z + av.w * bv.w;
        }
        feat[(rowbase + n0 + n_i) * WIN + wv] = acc;
        attnw[n_i][wv] = acc;
    }
    __syncthreads();

    // phase 3: xt window -> LDS bf16 (threads <224) || softmax (threads >=224)
    unsigned short* xts = (unsigned short*)&et[0][0];   // [38][256] bf16
    if (t < 224) {
        #pragma unroll
        for (int p = 0; p < 6; ++p) {
            const int j = t + p * 224;
            if (j < 1216) {
                const int r = j >> 5, c8 = j & 31;
                int g = n0 - HWIN + r;
                g = min(max(g, 0), NN - 1);
                const float* gp = &xt[(rowbase + g) * KK + c8 * 8];
                const float4 a = *(const float4*)(gp);
                const float4 b = *(const float4*)(gp + 4);
                *(uint4*)((char*)xts + r * 512 + c8 * 16) = pack8(a, b);
            }
        }
    } else {
        const int n_i = t - 224;
        const int n = n0 + n_i;
        float mx = -1e30f;
        #pragma unroll
        for (int wv = 0; wv < WIN; ++wv) {
            const int c = n + wv - HWIN;
            if (c >= 0 && c < NN) mx = fmaxf(mx, attnw[n_i][wv]);
        }
        float e[WIN];
        float esum = 0.f;
        #pragma unroll
        for (int wv = 0; wv < WIN; ++wv) {
            const int c = n + wv - HWIN;
            const bool valid = (c >= 0 && c < NN);
            e[wv] = valid ? expf(attnw[n_i][wv] - mx) : 0.f;
            esum += e[wv];
        }
        const float inv = 1.0f / esum;
        #pragma unroll
        for (int wv = 0; wv < WIN; ++wv) attnw[n_i][wv] = e[wv] * inv;
    }
    __syncthreads();

    // phase 4: out = alpha*x + (1-alpha) * sum_w attn[w] * xt_window (LDS)
    #pragma unroll
    for (int p = 0; p < 8; ++p) {
        const int idx = t + p * 256;
        const int n_i = idx >> 6, e4 = idx & 63;
        const int n = n0 + n_i;
        const float4 xv = *(const float4*)(&x[(rowbase + n) * KK + e4 * 4]);
        float4 acc = make_float4(0.f, 0.f, 0.f, 0.f);
        #pragma unroll
        for (int wv = 0; wv < WIN; ++wv) {
            const float aw = attnw[n_i][wv];
            const uint2 u = *(const uint2*)((const char*)xts + (n_i + wv) * 512 + e4 * 8);
            acc.x += aw * b2f_lo(u.x);
            acc.y += aw * b2f_hi(u.x);
            acc.z += aw * b2f_lo(u.y);
            acc.w += aw * b2f_hi(u.y);
        }
        float4 o;
        o.x = ALPHA * xv.x + (1.f - ALPHA) * acc.x;
        o.y = ALPHA * xv.y + (1.f - ALPHA) * acc.y;
        o.z = ALPHA * xv.z + (1.f - ALPHA) * acc.z;
        o.w = ALPHA * xv.w + (1.f - ALPHA) * acc.w;
        *(float4*)(&out[(rowbase + n) * KK + e4 * 4]) = o;
    }
}

// ---------------------------------------------------------------------------
extern "C" void kernel_launch(void* const* d_in, const int* in_sizes, int n_in,
                              void* d_out, int out_size, void* d_ws, size_t ws_size,
                              hipStream_t stream) {
    const float* x     = (const float*)d_in[0];
    const float* xt    = (const float*)d_in[1];
    const float* W     = (const float*)d_in[2];
    const float* bvec  = (const float*)d_in[3];
    const float* gamma = (const float*)d_in[4];
    const float* beta  = (const float*)d_in[5];

    float* out  = (float*)d_out;
    float* feat = out + (size_t)BB * NN * KK;

    char* ws = (char*)d_ws;
    unsigned short* h  = (unsigned short*)ws;                  // 32 MiB
    float* sums        = (float*)(ws + 33554432);              // 2 KiB
    unsigned char* Wfr = (unsigned char*)(ws + 33556480);      // 64 KiB

    hipMemsetAsync(sums, 0, 512 * sizeof(float), stream);
    k_prep<<<16, 256, 0, stream>>>(W, (uint4*)Wfr);
    k_embed<<<512, 512, 0, stream>>>(x, xt, (const uint4*)Wfr, bvec, h, sums);
    k_attn<<<2048, 256, 0, stream>>>(x, xt, h, sums, gamma, beta, out, feat);
}